// Round 5
// baseline (3364.579 us; speedup 1.0000x reference)
//
#include <hip/hip_runtime.h>
#include <hip/hip_bf16.h>

#define N_NODES   50000
#define N_EDGES   800000
#define N_GRAPHS  256
#define EMB       128
#define L_LAYERS  8
#define N_CLASSES 10
#define BN_EPS    1e-5f
#define NEG_SLOPE 0.01f
#define BM 64
#define NBLK ((N_NODES + BM - 1) / BM)   // 782 mlp blocks

#define FIX_SCALE   1.099511627776e12f     // 2^40
#define FIX_INV     9.094947017729282e-13f // 2^-40

// ---------------------------------------------------------------------------
// CSR build. csr entry order is nondeterministic (atomic cursor), but the
// fixed-point gather makes the aggregate bit-exact regardless of order.
// ---------------------------------------------------------------------------
__global__ void deg_kernel(const int* __restrict__ ei, int* __restrict__ deg) {
    int e = blockIdx.x * 256 + threadIdx.x;
    if (e < N_EDGES) atomicAdd(&deg[ei[N_EDGES + e]], 1);
}

__global__ void scan_kernel(const int* __restrict__ deg,
                            int* __restrict__ rowptr, int* __restrict__ cursor) {
    __shared__ int sums[256];
    __shared__ int offs[257];
    int t = threadIdx.x;
    const int chunk = (N_NODES + 255) / 256;
    int start = t * chunk;
    int end   = start + chunk; if (end > N_NODES) end = N_NODES;
    int s = 0;
    for (int i = start; i < end; ++i) s += deg[i];
    sums[t] = s;
    __syncthreads();
    if (t == 0) {
        int a = 0;
        for (int i = 0; i < 256; ++i) { offs[i] = a; a += sums[i]; }
        offs[256] = a;
    }
    __syncthreads();
    int a = offs[t];
    for (int i = start; i < end; ++i) {
        rowptr[i] = a; cursor[i] = a; a += deg[i];
    }
    if (t == 255) rowptr[N_NODES] = offs[256];
}

__global__ void scatter_kernel(const int* __restrict__ ei,
                               int* __restrict__ cursor, int* __restrict__ csr) {
    int e = blockIdx.x * 256 + threadIdx.x;
    if (e < N_EDGES) {
        int d = ei[N_EDGES + e];
        int s = ei[e];
        int p = atomicAdd(&cursor[d], 1);
        csr[p] = s;
    }
}

// ---------------------------------------------------------------------------
// GIN aggregate, fixed-point (order-independent): one wave per node.
// ---------------------------------------------------------------------------
__global__ __launch_bounds__(256) void agg_kernel(
        const float* __restrict__ x, const int* __restrict__ rowptr,
        const int* __restrict__ csr, float* __restrict__ hpre) {
    int wave = threadIdx.x >> 6;
    int lane = threadIdx.x & 63;
    int node = blockIdx.x * 4 + wave;
    if (node >= N_NODES) return;
    int beg = rowptr[node];
    int end = rowptr[node + 1];
    const float2* xp = (const float2*)x;
    long long a0 = 0, a1 = 0;
    int e = beg;
    for (; e + 1 < end; e += 2) {
        int s0 = csr[e], s1 = csr[e + 1];
        float2 v0 = xp[(size_t)s0 * 64 + lane];
        float2 v1 = xp[(size_t)s1 * 64 + lane];
        a0 += (long long)llrintf(v0.x * FIX_SCALE)
            + (long long)llrintf(v1.x * FIX_SCALE);
        a1 += (long long)llrintf(v0.y * FIX_SCALE)
            + (long long)llrintf(v1.y * FIX_SCALE);
    }
    if (e < end) {
        float2 v0 = xp[(size_t)csr[e] * 64 + lane];
        a0 += (long long)llrintf(v0.x * FIX_SCALE);
        a1 += (long long)llrintf(v0.y * FIX_SCALE);
    }
    float2 xv = xp[(size_t)node * 64 + lane];
    ((float2*)hpre)[(size_t)node * 64 + lane] =
        make_float2(xv.x + (float)a0 * FIX_INV, xv.y + (float)a1 * FIX_INV);
}

// ---------------------------------------------------------------------------
// MLP: H = leaky(HB @ W1 + b1) @ W2 + b2  (in place on HB)
// lane = row (64 rows/block), wave owns a 32-column strip -> weights are
// wave-uniform -> SGPR operand in v_fmac, only ONE ds_read_b32 per k-step.
// ---------------------------------------------------------------------------
__global__ __launch_bounds__(256) void mlp_kernel(
        float* __restrict__ HB,
        const float* __restrict__ W1, const float* __restrict__ b1,
        const float* __restrict__ W2, const float* __restrict__ b2,
        float* __restrict__ psum, float* __restrict__ psq,
        float* __restrict__ colsum, float* __restrict__ colsumsq,
        int* __restrict__ counter) {
    __shared__ float T[EMB][66];      // At / Tt / Ht reused: 33792 B
    __shared__ float red_s[2][EMB];   // 1 KB
    __shared__ float red_q[2][EMB];   // 1 KB
    __shared__ int   s_islast;

    int t    = threadIdx.x;
    int lane = t & 63;                       // row within tile
    int wv   = __builtin_amdgcn_readfirstlane(t >> 6);  // wave id -> uniform
    int row0 = blockIdx.x * BM;
    int valid = N_NODES - row0; if (valid > BM) valid = BM;

    // ---- stage A transposed: T[k][row] (coalesced global read) ----
    {
        const float4* Ag = (const float4*)HB;
        #pragma unroll
        for (int rep = 0; rep < 8; ++rep) {
            int v  = t + rep * 256;          // 0..2047
            int r  = v >> 5;                 // row 0..63
            int c4 = v & 31;                 // float4 index 0..31
            float4 val = (r < valid) ? Ag[(size_t)(row0 + r) * 32 + c4]
                                     : make_float4(0.f, 0.f, 0.f, 0.f);
            T[4 * c4 + 0][r] = val.x;
            T[4 * c4 + 1][r] = val.y;
            T[4 * c4 + 2][r] = val.z;
            T[4 * c4 + 3][r] = val.w;
        }
    }
    __syncthreads();

    float acc[32];
    #pragma unroll
    for (int j = 0; j < 32; ++j) acc[j] = 0.f;

    // ---- phase 1: T1 = leaky(A @ W1 + b1), cols [wv*32, wv*32+32) ----
    {
        const float* Wp = W1 + wv * 32;      // uniform pointer -> s_load
        #pragma unroll 2
        for (int k = 0; k < EMB; ++k) {
            float a = T[k][lane];
            #pragma unroll
            for (int j = 0; j < 32; ++j)
                acc[j] = fmaf(a, Wp[k * EMB + j], acc[j]);
        }
        const float* bp = b1 + wv * 32;
        #pragma unroll
        for (int j = 0; j < 32; ++j) {
            float v = acc[j] + bp[j];
            acc[j] = (v > 0.f) ? v : NEG_SLOPE * v;
        }
    }

    __syncthreads();                          // A-tile dead
    #pragma unroll
    for (int j = 0; j < 32; ++j) {            // write T transposed
        T[wv * 32 + j][lane] = acc[j];
        acc[j] = 0.f;
    }
    __syncthreads();

    // ---- phase 2: H = T1 @ W2 + b2 ----
    {
        const float* Wp = W2 + wv * 32;
        #pragma unroll 2
        for (int k = 0; k < EMB; ++k) {
            float a = T[k][lane];
            #pragma unroll
            for (int j = 0; j < 32; ++j)
                acc[j] = fmaf(a, Wp[k * EMB + j], acc[j]);
        }
        const float* bp = b2 + wv * 32;
        #pragma unroll
        for (int j = 0; j < 32; ++j) acc[j] += bp[j];
    }

    __syncthreads();                          // T1 dead
    #pragma unroll
    for (int j = 0; j < 32; ++j)              // write H transposed (Ht)
        T[wv * 32 + j][lane] = acc[j];
    __syncthreads();

    // ---- BN partials from Ht (fixed order within block) ----
    {
        int c    = t & 127;
        int half = t >> 7;
        float s = 0.f, q = 0.f;
        int rbeg = half * 32;
        int rend = rbeg + 32; if (rend > valid) rend = valid;
        for (int r = rbeg; r < rend; ++r) {
            float v = T[c][r];
            s += v; q += v * v;
        }
        red_s[half][c] = s;
        red_q[half][c] = q;
    }
    __syncthreads();
    if (t < EMB) {
        psum[blockIdx.x * EMB + t] = red_s[0][t] + red_s[1][t];
        psq [blockIdx.x * EMB + t] = red_q[0][t] + red_q[1][t];
    }

    // ---- coalesced store of H ----
    {
        float4* Hg = (float4*)HB;
        #pragma unroll
        for (int rep = 0; rep < 8; ++rep) {
            int v  = t + rep * 256;
            int r  = v >> 5;
            int c4 = v & 31;
            if (r < valid) {
                float4 o;
                o.x = T[4 * c4 + 0][r];
                o.y = T[4 * c4 + 1][r];
                o.z = T[4 * c4 + 2][r];
                o.w = T[4 * c4 + 3][r];
                Hg[(size_t)(row0 + r) * 32 + c4] = o;
            }
        }
    }

    // ---- last-block BN reduce (fixed order -> deterministic) ----
    __threadfence();
    if (t == 0) s_islast = (atomicAdd(counter, 1) == NBLK - 1) ? 1 : 0;
    __syncthreads();
    if (s_islast) {
        __threadfence();
        if (t < EMB) {
            float s = 0.f, q = 0.f;
            for (int b = 0; b < NBLK; ++b) {
                s += psum[b * EMB + t];
                q += psq[b * EMB + t];
            }
            colsum[t] = s;
            colsumsq[t] = q;
        }
    }
}

// ---------------------------------------------------------------------------
// BatchNorm + gumbel-argmax one-hot + graph max + next-x (2 nodes/block)
// ---------------------------------------------------------------------------
__global__ __launch_bounds__(256) void finalize_kernel(
        const float* __restrict__ h,
        const float* __restrict__ colsum, const float* __restrict__ colsumsq,
        const float* __restrict__ gamma, const float* __restrict__ beta,
        const float* __restrict__ gumbel_l, const int* __restrict__ batch,
        float* __restrict__ nc_out, float* __restrict__ gc_out,
        float* __restrict__ xnext) {
    __shared__ float wv[4];
    __shared__ int   wi[4];
    int t = threadIdx.x;
    int node = blockIdx.x * 2 + (t >> 7);
    int f = t & 127;

    float s  = colsum[f];
    float sq = colsumsq[f];
    const float invN = 1.f / (float)N_NODES;
    float mu  = s * invN;
    float var = sq * invN - mu * mu;
    float inv = rsqrtf(var + BN_EPS);

    float hv = h[(size_t)node * EMB + f];
    float hb = (hv - mu) * inv * gamma[f] + beta[f];
    float y  = hb + gumbel_l[(size_t)node * EMB + f];   // TAU == 1.0

    float bv = y; int bi = f;
    #pragma unroll
    for (int off = 32; off > 0; off >>= 1) {
        float ov = __shfl_down(bv, off);
        int   oi = __shfl_down(bi, off);
        if (ov > bv || (ov == bv && oi < bi)) { bv = ov; bi = oi; }
    }
    if ((t & 63) == 0) { wv[t >> 6] = bv; wi[t >> 6] = bi; }
    __syncthreads();
    int base = (t >> 7) * 2;
    float v0 = wv[base], v1 = wv[base + 1];
    int   i0 = wi[base], i1 = wi[base + 1];
    int amax = (v1 > v0 || (v1 == v0 && i1 < i0)) ? i1 : i0;

    nc_out[(size_t)node * EMB + f] = (f == amax) ? 1.0f : 0.0f;
    xnext[(size_t)node * EMB + f]  = (hb > 0.f) ? hb : NEG_SLOPE * hb;
    if (f == 0) atomicExch(&gc_out[(size_t)batch[node] * EMB + amax], 1.0f);
}

// ---------------------------------------------------------------------------
__global__ __launch_bounds__(128) void logits_kernel(
        const float* __restrict__ gc, const float* __restrict__ W,
        const float* __restrict__ b, float* __restrict__ out) {
    __shared__ float row[EMB];
    int g = blockIdx.x;
    int t = threadIdx.x;
    row[t] = gc[g * EMB + t];
    __syncthreads();
    if (t < N_CLASSES) {
        float acc = b[t];
        for (int k = 0; k < EMB; ++k) acc += row[k] * W[k * N_CLASSES + t];
        out[g * N_CLASSES + t] = acc;
    }
}

// ---------------------------------------------------------------------------
extern "C" void kernel_launch(void* const* d_in, const int* in_sizes, int n_in,
                              void* d_out, int out_size, void* d_ws, size_t ws_size,
                              hipStream_t stream) {
    const float* x_in    = (const float*)d_in[0];
    const int*   ei      = (const int*)  d_in[1];
    const int*   batch   = (const int*)  d_in[2];
    const float* W1      = (const float*)d_in[3];
    const float* b1      = (const float*)d_in[4];
    const float* W2      = (const float*)d_in[5];
    const float* b2      = (const float*)d_in[6];
    const float* gamma   = (const float*)d_in[7];
    const float* beta    = (const float*)d_in[8];
    const float* gumbel  = (const float*)d_in[9];
    const float* dW      = (const float*)d_in[10];
    const float* db      = (const float*)d_in[11];

    float* out = (float*)d_out;
    const size_t NC_OFF = (size_t)N_GRAPHS * N_CLASSES;
    const size_t GC_OFF = NC_OFF + (size_t)L_LAYERS * N_NODES * EMB;
    float* logits_out = out;
    float* nc_out     = out + NC_OFF;
    float* gc_out     = out + GC_OFF;

    // workspace layout
    float* xbuf    = (float*)d_ws;                    // 6.4M
    float* hbuf    = xbuf + (size_t)N_NODES * EMB;    // 6.4M
    float* psum    = hbuf + (size_t)N_NODES * EMB;    // NBLK*128
    float* psq     = psum + (size_t)NBLK * EMB;       // NBLK*128
    float* colsum  = psq + (size_t)NBLK * EMB;        // 128
    float* colsumsq= colsum + EMB;                    // 128
    int*   counters= (int*)(colsumsq + EMB);          // 8
    int*   rowptr  = counters + L_LAYERS;             // 50001
    int*   cursor  = rowptr + (N_NODES + 1);          // 50000
    int*   csr     = cursor + N_NODES;                // 800000
    int*   deg     = csr + N_EDGES;                   // 50000

    hipMemsetAsync(deg, 0, N_NODES * sizeof(int), stream);
    hipMemsetAsync(counters, 0, L_LAYERS * sizeof(int), stream);
    hipMemsetAsync(gc_out, 0,
                   (size_t)L_LAYERS * N_GRAPHS * EMB * sizeof(float), stream);

    deg_kernel<<<(N_EDGES + 255) / 256, 256, 0, stream>>>(ei, deg);
    scan_kernel<<<1, 256, 0, stream>>>(deg, rowptr, cursor);
    scatter_kernel<<<(N_EDGES + 255) / 256, 256, 0, stream>>>(ei, cursor, csr);

    for (int l = 0; l < L_LAYERS; ++l) {
        const float* xsrc = (l == 0) ? x_in : xbuf;
        agg_kernel<<<(N_NODES + 3) / 4, 256, 0, stream>>>(xsrc, rowptr, csr, hbuf);
        mlp_kernel<<<NBLK, 256, 0, stream>>>(
            hbuf,
            W1 + (size_t)l * EMB * EMB, b1 + (size_t)l * EMB,
            W2 + (size_t)l * EMB * EMB, b2 + (size_t)l * EMB,
            psum, psq, colsum, colsumsq, counters + l);
        finalize_kernel<<<N_NODES / 2, 256, 0, stream>>>(
            hbuf, colsum, colsumsq,
            gamma + (size_t)l * EMB, beta + (size_t)l * EMB,
            gumbel + (size_t)l * N_NODES * EMB, batch,
            nc_out + (size_t)l * N_NODES * EMB,
            gc_out + (size_t)l * N_GRAPHS * EMB,
            xbuf);
    }

    logits_kernel<<<N_GRAPHS, 128, 0, stream>>>(
        gc_out + (size_t)(L_LAYERS - 1) * N_GRAPHS * EMB, dW, db, logits_out);
}

// Round 6
// 3172.008 us; speedup vs baseline: 1.0607x; 1.0607x over previous
//
#include <hip/hip_runtime.h>
#include <hip/hip_bf16.h>

#define N_NODES   50000
#define N_EDGES   800000
#define N_GRAPHS  256
#define EMB       128
#define L_LAYERS  8
#define N_CLASSES 10
#define BN_EPS    1e-5f
#define NEG_SLOPE 0.01f
#define BM 64
#define NBLK ((N_NODES + BM - 1) / BM)   // 782 mlp blocks

#define FIX_SCALE   1.099511627776e12f     // 2^40
#define FIX_INV     9.094947017729282e-13f // 2^-40

typedef short  s8v  __attribute__((ext_vector_type(8)));   // 8 bf16 (4 VGPR)
typedef float  f4v  __attribute__((ext_vector_type(4)));   // MFMA acc

// 3-way bf16 split: x ~= hi + mid + lo, each RNE-rounded; residuals exact.
__device__ __forceinline__ void split3(float x, unsigned short& hb,
                                       unsigned short& mb, unsigned short& lb) {
    unsigned u = __float_as_uint(x);
    hb = (unsigned short)((u + 0x7FFFu + ((u >> 16) & 1u)) >> 16);
    float hf = __uint_as_float(((unsigned)hb) << 16);
    float r1 = x - hf;
    unsigned u1 = __float_as_uint(r1);
    mb = (unsigned short)((u1 + 0x7FFFu + ((u1 >> 16) & 1u)) >> 16);
    float mf = __uint_as_float(((unsigned)mb) << 16);
    float r2 = r1 - mf;
    unsigned u2 = __float_as_uint(r2);
    lb = (unsigned short)((u2 + 0x7FFFu + ((u2 >> 16) & 1u)) >> 16);
}

// ---------------------------------------------------------------------------
// CSR build (csr order nondeterministic; fixed-point gather is order-proof)
// ---------------------------------------------------------------------------
__global__ void deg_kernel(const int* __restrict__ ei, int* __restrict__ deg) {
    int e = blockIdx.x * 256 + threadIdx.x;
    if (e < N_EDGES) atomicAdd(&deg[ei[N_EDGES + e]], 1);
}

__global__ void scan_kernel(const int* __restrict__ deg,
                            int* __restrict__ rowptr, int* __restrict__ cursor) {
    __shared__ int sums[256];
    __shared__ int offs[257];
    int t = threadIdx.x;
    const int chunk = (N_NODES + 255) / 256;
    int start = t * chunk;
    int end   = start + chunk; if (end > N_NODES) end = N_NODES;
    int s = 0;
    for (int i = start; i < end; ++i) s += deg[i];
    sums[t] = s;
    __syncthreads();
    if (t == 0) {
        int a = 0;
        for (int i = 0; i < 256; ++i) { offs[i] = a; a += sums[i]; }
        offs[256] = a;
    }
    __syncthreads();
    int a = offs[t];
    for (int i = start; i < end; ++i) {
        rowptr[i] = a; cursor[i] = a; a += deg[i];
    }
    if (t == 255) rowptr[N_NODES] = offs[256];
}

__global__ void scatter_kernel(const int* __restrict__ ei,
                               int* __restrict__ cursor, int* __restrict__ csr) {
    int e = blockIdx.x * 256 + threadIdx.x;
    if (e < N_EDGES) {
        int d = ei[N_EDGES + e];
        int s = ei[e];
        int p = atomicAdd(&cursor[d], 1);
        csr[p] = s;
    }
}

// ---------------------------------------------------------------------------
// Pre-split all weights into TRANSPOSED bf16 planes: Wt[mat*3+p][n][k]
// mat = l*2+g  (g=0: W1, g=1: W2), p = hi/mid/lo
// ---------------------------------------------------------------------------
__global__ __launch_bounds__(256) void splitw_kernel(
        const float* __restrict__ W1, const float* __restrict__ W2,
        unsigned short* __restrict__ Wt) {
    int idx = blockIdx.x * 256 + threadIdx.x;     // 16 * 16384
    int mat = idx >> 14;
    int rem = idx & 16383;
    int k = rem >> 7;
    int n = rem & 127;
    int l = mat >> 1, g = mat & 1;
    float v = (g ? W2 : W1)[(size_t)l * 16384 + k * 128 + n];
    unsigned short hb, mb, lb;
    split3(v, hb, mb, lb);
    size_t base = (size_t)mat * 3 * 16384 + (size_t)n * 128 + k;
    Wt[base]             = hb;
    Wt[base + 16384]     = mb;
    Wt[base + 32768]     = lb;
}

// ---------------------------------------------------------------------------
// GIN aggregate (fixed-point, order-independent) -> 3 bf16 planes [node][128]
// ---------------------------------------------------------------------------
__global__ __launch_bounds__(256) void agg_kernel(
        const float* __restrict__ x, const int* __restrict__ rowptr,
        const int* __restrict__ csr,
        unsigned short* __restrict__ Ah, unsigned short* __restrict__ Am,
        unsigned short* __restrict__ Al) {
    int wave = threadIdx.x >> 6;
    int lane = threadIdx.x & 63;
    int node = blockIdx.x * 4 + wave;
    if (node >= N_NODES) return;
    int beg = rowptr[node];
    int end = rowptr[node + 1];
    const float2* xp = (const float2*)x;
    long long a0 = 0, a1 = 0;
    int e = beg;
    for (; e + 1 < end; e += 2) {
        int s0 = csr[e], s1 = csr[e + 1];
        float2 v0 = xp[(size_t)s0 * 64 + lane];
        float2 v1 = xp[(size_t)s1 * 64 + lane];
        a0 += (long long)llrintf(v0.x * FIX_SCALE)
            + (long long)llrintf(v1.x * FIX_SCALE);
        a1 += (long long)llrintf(v0.y * FIX_SCALE)
            + (long long)llrintf(v1.y * FIX_SCALE);
    }
    if (e < end) {
        float2 v0 = xp[(size_t)csr[e] * 64 + lane];
        a0 += (long long)llrintf(v0.x * FIX_SCALE);
        a1 += (long long)llrintf(v0.y * FIX_SCALE);
    }
    float2 xv = xp[(size_t)node * 64 + lane];
    float vx = xv.x + (float)a0 * FIX_INV;
    float vy = xv.y + (float)a1 * FIX_INV;
    unsigned short h0, m0, l0, h1, m1, l1;
    split3(vx, h0, m0, l0);
    split3(vy, h1, m1, l1);
    unsigned pos = (unsigned)node * 64 + lane;   // uint (2 shorts) index
    ((unsigned*)Ah)[pos] = (unsigned)h0 | ((unsigned)h1 << 16);
    ((unsigned*)Am)[pos] = (unsigned)m0 | ((unsigned)m1 << 16);
    ((unsigned*)Al)[pos] = (unsigned)l0 | ((unsigned)l1 << 16);
}

// ---------------------------------------------------------------------------
// MFMA MLP: H = leaky(A @ W1 + b1) @ W2 + b2, fp32-faithful via 6 products.
// Block: 256 thr, 64 rows; wave w owns cols [w*32, w*32+32).
// ---------------------------------------------------------------------------
__global__ __launch_bounds__(256) void mlp_kernel(
        const unsigned short* __restrict__ Ah,
        const unsigned short* __restrict__ Am,
        const unsigned short* __restrict__ Al,
        const unsigned short* __restrict__ Wt1,
        const unsigned short* __restrict__ Wt2,
        const float* __restrict__ b1, const float* __restrict__ b2,
        float* __restrict__ hbuf,
        float* __restrict__ psum, float* __restrict__ psq,
        float* __restrict__ colsum, float* __restrict__ colsumsq,
        int* __restrict__ counter) {
    __shared__ unsigned short Apl[3][64][136];  // 136 = 128 + 8 pad (row 272 B)
    __shared__ float red_s[128][4];
    __shared__ float red_q[128][4];
    __shared__ int   s_islast;

    int t    = threadIdx.x;
    int lane = t & 63;
    int w    = t >> 6;
    int quad = lane >> 4;
    int l16  = lane & 15;
    int row0 = blockIdx.x * BM;
    int valid = N_NODES - row0; if (valid > BM) valid = BM;

    // ---- stage A planes (coalesced 16B) ----
    #pragma unroll
    for (int rep = 0; rep < 12; ++rep) {
        int v   = t + rep * 256;       // 0..3071
        int p   = v >> 10;
        int rem = v & 1023;
        int r   = rem >> 4;
        int c8  = rem & 15;
        const unsigned short* sp = (p == 0) ? Ah : (p == 1) ? Am : Al;
        int4 val = (r < valid)
            ? *(const int4*)(sp + (((size_t)(row0 + r)) << 7) + (c8 << 3))
            : make_int4(0, 0, 0, 0);
        *(int4*)&Apl[p][r][c8 << 3] = val;
    }
    __syncthreads();

    f4v acc[4][2];
    #pragma unroll
    for (int mt = 0; mt < 4; ++mt)
        #pragma unroll
        for (int nt = 0; nt < 2; ++nt) acc[mt][nt] = (f4v){0.f, 0.f, 0.f, 0.f};

    // ================= GEMM 1: A @ W1 =================
    #pragma unroll
    for (int kc = 0; kc < 4; ++kc) {
        int kb = kc * 32 + quad * 8;
        const unsigned short* wb = Wt1 + ((size_t)(w * 32 + l16)) * 128 + kb;
        s8v bh0 = *(const s8v*)(wb);
        s8v bm0 = *(const s8v*)(wb + 16384);
        s8v bl0 = *(const s8v*)(wb + 32768);
        s8v bh1 = *(const s8v*)(wb + 2048);
        s8v bm1 = *(const s8v*)(wb + 16384 + 2048);
        s8v bl1 = *(const s8v*)(wb + 32768 + 2048);
        #pragma unroll
        for (int mt = 0; mt < 4; ++mt) {
            const unsigned short* ab = &Apl[0][mt * 16 + l16][kb];
            s8v ah = *(const s8v*)(ab);
            s8v am = *(const s8v*)(ab + 8704);
            s8v al = *(const s8v*)(ab + 17408);
            f4v c0 = acc[mt][0];
            c0 = __builtin_amdgcn_mfma_f32_16x16x32_bf16(al, bh0, c0, 0, 0, 0);
            c0 = __builtin_amdgcn_mfma_f32_16x16x32_bf16(ah, bl0, c0, 0, 0, 0);
            c0 = __builtin_amdgcn_mfma_f32_16x16x32_bf16(am, bm0, c0, 0, 0, 0);
            c0 = __builtin_amdgcn_mfma_f32_16x16x32_bf16(am, bh0, c0, 0, 0, 0);
            c0 = __builtin_amdgcn_mfma_f32_16x16x32_bf16(ah, bm0, c0, 0, 0, 0);
            c0 = __builtin_amdgcn_mfma_f32_16x16x32_bf16(ah, bh0, c0, 0, 0, 0);
            acc[mt][0] = c0;
            f4v c1 = acc[mt][1];
            c1 = __builtin_amdgcn_mfma_f32_16x16x32_bf16(al, bh1, c1, 0, 0, 0);
            c1 = __builtin_amdgcn_mfma_f32_16x16x32_bf16(ah, bl1, c1, 0, 0, 0);
            c1 = __builtin_amdgcn_mfma_f32_16x16x32_bf16(am, bm1, c1, 0, 0, 0);
            c1 = __builtin_amdgcn_mfma_f32_16x16x32_bf16(am, bh1, c1, 0, 0, 0);
            c1 = __builtin_amdgcn_mfma_f32_16x16x32_bf16(ah, bm1, c1, 0, 0, 0);
            c1 = __builtin_amdgcn_mfma_f32_16x16x32_bf16(ah, bh1, c1, 0, 0, 0);
            acc[mt][1] = c1;
        }
    }

    // ---- epilogue 1: bias + leaky, split T into LDS planes ----
    __syncthreads();   // all Apl reads done before overwrite
    #pragma unroll
    for (int mt = 0; mt < 4; ++mt) {
        #pragma unroll
        for (int nt = 0; nt < 2; ++nt) {
            int n = w * 32 + nt * 16 + l16;
            float bias = b1[n];
            #pragma unroll
            for (int r = 0; r < 4; ++r) {
                float v = acc[mt][nt][r] + bias;
                v = (v > 0.f) ? v : NEG_SLOPE * v;
                unsigned short hb, mb, lb;
                split3(v, hb, mb, lb);
                int mrow = mt * 16 + quad * 4 + r;
                Apl[0][mrow][n] = hb;
                Apl[1][mrow][n] = mb;
                Apl[2][mrow][n] = lb;
            }
            acc[mt][nt] = (f4v){0.f, 0.f, 0.f, 0.f};
        }
    }
    __syncthreads();

    // ================= GEMM 2: T @ W2 =================
    #pragma unroll
    for (int kc = 0; kc < 4; ++kc) {
        int kb = kc * 32 + quad * 8;
        const unsigned short* wb = Wt2 + ((size_t)(w * 32 + l16)) * 128 + kb;
        s8v bh0 = *(const s8v*)(wb);
        s8v bm0 = *(const s8v*)(wb + 16384);
        s8v bl0 = *(const s8v*)(wb + 32768);
        s8v bh1 = *(const s8v*)(wb + 2048);
        s8v bm1 = *(const s8v*)(wb + 16384 + 2048);
        s8v bl1 = *(const s8v*)(wb + 32768 + 2048);
        #pragma unroll
        for (int mt = 0; mt < 4; ++mt) {
            const unsigned short* ab = &Apl[0][mt * 16 + l16][kb];
            s8v ah = *(const s8v*)(ab);
            s8v am = *(const s8v*)(ab + 8704);
            s8v al = *(const s8v*)(ab + 17408);
            f4v c0 = acc[mt][0];
            c0 = __builtin_amdgcn_mfma_f32_16x16x32_bf16(al, bh0, c0, 0, 0, 0);
            c0 = __builtin_amdgcn_mfma_f32_16x16x32_bf16(ah, bl0, c0, 0, 0, 0);
            c0 = __builtin_amdgcn_mfma_f32_16x16x32_bf16(am, bm0, c0, 0, 0, 0);
            c0 = __builtin_amdgcn_mfma_f32_16x16x32_bf16(am, bh0, c0, 0, 0, 0);
            c0 = __builtin_amdgcn_mfma_f32_16x16x32_bf16(ah, bm0, c0, 0, 0, 0);
            c0 = __builtin_amdgcn_mfma_f32_16x16x32_bf16(ah, bh0, c0, 0, 0, 0);
            acc[mt][0] = c0;
            f4v c1 = acc[mt][1];
            c1 = __builtin_amdgcn_mfma_f32_16x16x32_bf16(al, bh1, c1, 0, 0, 0);
            c1 = __builtin_amdgcn_mfma_f32_16x16x32_bf16(ah, bl1, c1, 0, 0, 0);
            c1 = __builtin_amdgcn_mfma_f32_16x16x32_bf16(am, bm1, c1, 0, 0, 0);
            c1 = __builtin_amdgcn_mfma_f32_16x16x32_bf16(am, bh1, c1, 0, 0, 0);
            c1 = __builtin_amdgcn_mfma_f32_16x16x32_bf16(ah, bm1, c1, 0, 0, 0);
            c1 = __builtin_amdgcn_mfma_f32_16x16x32_bf16(ah, bh1, c1, 0, 0, 0);
            acc[mt][1] = c1;
        }
    }

    // ---- epilogue 2: bias, store H, BN partials ----
    float cs[2] = {0.f, 0.f}, cq[2] = {0.f, 0.f};
    #pragma unroll
    for (int nt = 0; nt < 2; ++nt) {
        int n = w * 32 + nt * 16 + l16;
        float bias = b2[n];
        #pragma unroll
        for (int mt = 0; mt < 4; ++mt) {
            #pragma unroll
            for (int r = 0; r < 4; ++r) {
                int mrow = mt * 16 + quad * 4 + r;
                if (mrow < valid) {
                    float v = acc[mt][nt][r] + bias;
                    hbuf[((size_t)(row0 + mrow)) * 128 + n] = v;
                    cs[nt] += v;
                    cq[nt] += v * v;
                }
            }
        }
        red_s[n][quad] = cs[nt];
        red_q[n][quad] = cq[nt];
    }
    __syncthreads();
    if (t < EMB) {
        psum[blockIdx.x * EMB + t] = (red_s[t][0] + red_s[t][1])
                                   + (red_s[t][2] + red_s[t][3]);
        psq [blockIdx.x * EMB + t] = (red_q[t][0] + red_q[t][1])
                                   + (red_q[t][2] + red_q[t][3]);
    }

    // ---- last-block BN reduce (fixed order -> deterministic) ----
    __threadfence();
    if (t == 0) s_islast = (atomicAdd(counter, 1) == NBLK - 1) ? 1 : 0;
    __syncthreads();
    if (s_islast) {
        __threadfence();
        if (t < EMB) {
            float s = 0.f, q = 0.f;
            for (int b = 0; b < NBLK; ++b) {
                s += psum[b * EMB + t];
                q += psq[b * EMB + t];
            }
            colsum[t] = s;
            colsumsq[t] = q;
        }
    }
}

// ---------------------------------------------------------------------------
// BatchNorm + gumbel-argmax one-hot + graph max + next-x (2 nodes/block)
// ---------------------------------------------------------------------------
__global__ __launch_bounds__(256) void finalize_kernel(
        const float* __restrict__ h,
        const float* __restrict__ colsum, const float* __restrict__ colsumsq,
        const float* __restrict__ gamma, const float* __restrict__ beta,
        const float* __restrict__ gumbel_l, const int* __restrict__ batch,
        float* __restrict__ nc_out, float* __restrict__ gc_out,
        float* __restrict__ xnext) {
    __shared__ float wv[4];
    __shared__ int   wi[4];
    int t = threadIdx.x;
    int node = blockIdx.x * 2 + (t >> 7);
    int f = t & 127;

    float s  = colsum[f];
    float sq = colsumsq[f];
    const float invN = 1.f / (float)N_NODES;
    float mu  = s * invN;
    float var = sq * invN - mu * mu;
    float inv = rsqrtf(var + BN_EPS);

    float hv = h[(size_t)node * EMB + f];
    float hb = (hv - mu) * inv * gamma[f] + beta[f];
    float y  = hb + gumbel_l[(size_t)node * EMB + f];   // TAU == 1.0

    float bv = y; int bi = f;
    #pragma unroll
    for (int off = 32; off > 0; off >>= 1) {
        float ov = __shfl_down(bv, off);
        int   oi = __shfl_down(bi, off);
        if (ov > bv || (ov == bv && oi < bi)) { bv = ov; bi = oi; }
    }
    if ((t & 63) == 0) { wv[t >> 6] = bv; wi[t >> 6] = bi; }
    __syncthreads();
    int base = (t >> 7) * 2;
    float v0 = wv[base], v1 = wv[base + 1];
    int   i0 = wi[base], i1 = wi[base + 1];
    int amax = (v1 > v0 || (v1 == v0 && i1 < i0)) ? i1 : i0;

    nc_out[(size_t)node * EMB + f] = (f == amax) ? 1.0f : 0.0f;
    xnext[(size_t)node * EMB + f]  = (hb > 0.f) ? hb : NEG_SLOPE * hb;
    if (f == 0) atomicExch(&gc_out[(size_t)batch[node] * EMB + amax], 1.0f);
}

// ---------------------------------------------------------------------------
__global__ __launch_bounds__(128) void logits_kernel(
        const float* __restrict__ gc, const float* __restrict__ W,
        const float* __restrict__ b, float* __restrict__ out) {
    __shared__ float row[EMB];
    int g = blockIdx.x;
    int t = threadIdx.x;
    row[t] = gc[g * EMB + t];
    __syncthreads();
    if (t < N_CLASSES) {
        float acc = b[t];
        for (int k = 0; k < EMB; ++k) acc += row[k] * W[k * N_CLASSES + t];
        out[g * N_CLASSES + t] = acc;
    }
}

// ---------------------------------------------------------------------------
extern "C" void kernel_launch(void* const* d_in, const int* in_sizes, int n_in,
                              void* d_out, int out_size, void* d_ws, size_t ws_size,
                              hipStream_t stream) {
    const float* x_in    = (const float*)d_in[0];
    const int*   ei      = (const int*)  d_in[1];
    const int*   batch   = (const int*)  d_in[2];
    const float* W1      = (const float*)d_in[3];
    const float* b1      = (const float*)d_in[4];
    const float* W2      = (const float*)d_in[5];
    const float* b2      = (const float*)d_in[6];
    const float* gamma   = (const float*)d_in[7];
    const float* beta    = (const float*)d_in[8];
    const float* gumbel  = (const float*)d_in[9];
    const float* dW      = (const float*)d_in[10];
    const float* db      = (const float*)d_in[11];

    float* out = (float*)d_out;
    const size_t NC_OFF = (size_t)N_GRAPHS * N_CLASSES;
    const size_t GC_OFF = NC_OFF + (size_t)L_LAYERS * N_NODES * EMB;
    float* logits_out = out;
    float* nc_out     = out + NC_OFF;
    float* gc_out     = out + GC_OFF;

    // workspace layout (bytes)
    char* ws = (char*)d_ws;
    size_t off = 0;
    float* xbuf = (float*)(ws + off);          off += (size_t)N_NODES * EMB * 4;   // 25.6 MB
    float* hbuf = (float*)(ws + off);          off += (size_t)N_NODES * EMB * 4;   // 25.6 MB
    unsigned short* Agh = (unsigned short*)(ws + off); off += (size_t)N_NODES * EMB * 2;
    unsigned short* Agm = (unsigned short*)(ws + off); off += (size_t)N_NODES * EMB * 2;
    unsigned short* Agl = (unsigned short*)(ws + off); off += (size_t)N_NODES * EMB * 2;
    unsigned short* Wt  = (unsigned short*)(ws + off); off += (size_t)16 * 3 * 16384 * 2;
    float* psum   = (float*)(ws + off);        off += (size_t)NBLK * EMB * 4;
    float* psq    = (float*)(ws + off);        off += (size_t)NBLK * EMB * 4;
    float* colsum = (float*)(ws + off);        off += 512;
    float* colsumsq = (float*)(ws + off);      off += 512;
    int* counters = (int*)(ws + off);          off += 64;
    int* rowptr   = (int*)(ws + off);          off += (size_t)(N_NODES + 1) * 4 + 60;
    int* cursor   = (int*)(ws + off);          off += (size_t)N_NODES * 4;
    int* csr      = (int*)(ws + off);          off += (size_t)N_EDGES * 4;
    int* deg      = (int*)(ws + off);          off += (size_t)N_NODES * 4;

    hipMemsetAsync(deg, 0, N_NODES * sizeof(int), stream);
    hipMemsetAsync(counters, 0, L_LAYERS * sizeof(int), stream);
    hipMemsetAsync(gc_out, 0,
                   (size_t)L_LAYERS * N_GRAPHS * EMB * sizeof(float), stream);

    deg_kernel<<<(N_EDGES + 255) / 256, 256, 0, stream>>>(ei, deg);
    scan_kernel<<<1, 256, 0, stream>>>(deg, rowptr, cursor);
    scatter_kernel<<<(N_EDGES + 255) / 256, 256, 0, stream>>>(ei, cursor, csr);
    splitw_kernel<<<(16 * 16384) / 256, 256, 0, stream>>>(W1, W2, Wt);

    for (int l = 0; l < L_LAYERS; ++l) {
        const float* xsrc = (l == 0) ? x_in : xbuf;
        agg_kernel<<<(N_NODES + 3) / 4, 256, 0, stream>>>(
            xsrc, rowptr, csr, Agh, Agm, Agl);
        mlp_kernel<<<NBLK, 256, 0, stream>>>(
            Agh, Agm, Agl,
            Wt + (size_t)(l * 2 + 0) * 3 * 16384,
            Wt + (size_t)(l * 2 + 1) * 3 * 16384,
            b1 + (size_t)l * EMB, b2 + (size_t)l * EMB,
            hbuf, psum, psq, colsum, colsumsq, counters + l);
        finalize_kernel<<<N_NODES / 2, 256, 0, stream>>>(
            hbuf, colsum, colsumsq,
            gamma + (size_t)l * EMB, beta + (size_t)l * EMB,
            gumbel + (size_t)l * N_NODES * EMB, batch,
            nc_out + (size_t)l * N_NODES * EMB,
            gc_out + (size_t)l * N_GRAPHS * EMB,
            xbuf);
    }

    logits_kernel<<<N_GRAPHS, 128, 0, stream>>>(
        gc_out + (size_t)(L_LAYERS - 1) * N_GRAPHS * EMB, dW, db, logits_out);
}